// Round 1
// baseline (286.399 us; speedup 1.0000x reference)
//
#include <hip/hip_runtime.h>

// ChebyKANLayer: y[t,o] = bias[o] + sum_k A[t,k]*B[k,o], K=8192, k=i*8+(d-1), d=1..8.
// R7: materialize A (bf16 basis, fragment-packed per 128x64 K-tile) in prep;
// gemm = counted-vmcnt pipelined 128x128 tile, A via global_load_lds dbuf,
// B direct global->reg with 2-tile prefetch, setprio MFMA clusters, XCD swizzle.

typedef __bf16 bf16;
typedef __bf16 bf16x8 __attribute__((ext_vector_type(8)));
typedef float f32x2 __attribute__((ext_vector_type(2)));
typedef float f32x4 __attribute__((ext_vector_type(4)));
typedef float f32x16 __attribute__((ext_vector_type(16)));

#define MFMA __builtin_amdgcn_mfma_f32_32x32x16_bf16

__device__ __forceinline__ void g2lds16(const void* g, void* l) {
  __builtin_amdgcn_global_load_lds(
      (const __attribute__((address_space(1))) unsigned int*)g,
      (__attribute__((address_space(3))) unsigned int*)l, 16, 0, 0);
}

__device__ __forceinline__ float fast_tanh(float a) {
  float e = __expf(a + a);
  return 1.f - 2.f * __builtin_amdgcn_rcpf(e + 1.f);   // saturating, NaN-free
}

// ============================ NEW PATH ============================
// A global layout: [mb 0..63][kt 0..127][tile image 8192 bf16], tile image:
//   elem(((ks*4 + m32)*2 + h)*32 + ml)*8 + j  where rows r: m32=(r&127)>>5, ml=r&31,
//   k-local = 16*ks + 8*h + j  (i = kt*8 + 2*ks + h, d = j+1).
// B global layout: [nb 0..7][kt 0..127][tile image 8192 bf16], same k mapping,
//   cols: n32=(o&127)>>5, ml=o&31.
// bias_p[p][o] = sum_{i in 32-block p} C[i][o][0].

__global__ __launch_bounds__(256)
void cheby_prep2(const float* __restrict__ x, const float* __restrict__ C,
                 bf16* __restrict__ A, bf16* __restrict__ B,
                 float* __restrict__ bias_p) {
  const int bid = blockIdx.x, tid = threadIdx.x;
  if (bid < 512) {                                   // ---- A-gen: 128 rows x 128 i per block
    const int mb = bid >> 3, ig = bid & 7;
    const int rl = tid & 127, ih = tid >> 7;
    const int m32 = rl >> 5, ml = rl & 31;
    const int i_base = ig * 128 + ih * 64;
    const float* xp = x + (size_t)(mb * 128 + rl) * 1024 + i_base;
    bf16* aout = A + (size_t)mb * 128 * 8192;
    #pragma unroll 2
    for (int q = 0; q < 16; ++q) {
      f32x4 xv = *(const f32x4*)(xp + q * 4);
      #pragma unroll
      for (int j = 0; j < 4; ++j) {
        const int ia = i_base + q * 4 + j;
        const int kt = ia >> 3, cc = ia & 7;
        float z = fast_tanh(xv[j]);
        float z2 = z + z, pv = 1.f, cv = z;
        bf16x8 v;
        #pragma unroll
        for (int d = 0; d < 8; ++d) {
          v[d] = (bf16)cv;
          float nx = z2 * cv - pv; pv = cv; cv = nx;
        }
        const int widx = (((cc >> 1) * 4 + m32) * 2 + (cc & 1)) * 32 + ml;
        *(bf16x8*)(aout + (size_t)kt * 8192 + widx * 8) = v;
      }
    }
    return;
  }
  // ---- B repack + bias partials: 32 i x 32 o per block (1024 blocks)
  const int b2 = bid - 512;
  __shared__ float tile[32][292];
  const int i0 = (b2 >> 5) * 32, o0 = (b2 & 31) * 32;
  {
    const int r = tid >> 3, seg = tid & 7;
    const float* src = C + (size_t)(i0 + r) * 9216 + (size_t)o0 * 9 + seg * 36;
    float* dst = &tile[r][seg * 36];
    #pragma unroll
    for (int v = 0; v < 9; ++v) *(f32x4*)(dst + v * 4) = *(const f32x4*)(src + v * 4);
  }
  __syncthreads();
  #pragma unroll
  for (int j = 0; j < 4; ++j) {
    int e = tid + 256 * j;
    int il = e >> 5, ol = e & 31;
    int i = i0 + il, o = o0 + ol;
    bf16x8 v;
    #pragma unroll
    for (int d = 0; d < 8; ++d) v[d] = (bf16)tile[il][ol * 9 + 1 + d];
    const int cc = i & 7;
    size_t tnum = (size_t)(o >> 7) * 128 + (i >> 3);
    const int widx = (((cc >> 1) * 4 + ((o & 127) >> 5)) * 2 + (cc & 1)) * 32 + (o & 31);
    *(bf16x8*)(B + tnum * 8192 + widx * 8) = v;
  }
  if (tid < 32) {
    float s = 0.f;
    #pragma unroll
    for (int i = 0; i < 32; ++i) s += tile[i][tid * 9];
    bias_p[(size_t)(b2 >> 5) * 1024 + o0 + tid] = s;
  }
}

// ---- GEMM: 128x128 tile, 256 thr (2x2 waves, wave 64x64), 2 blk/CU.
// A dbuf in LDS via global_load_lds; B direct global->reg, 2-tile prefetch.
// Per-tile: issue A(t+1) [4 g2lds]; vmcnt(12); barrier; 2 MFMA phases; issue B(t+2); barrier.
__global__ __launch_bounds__(256, 2)
void cheby_gemm2(const bf16* __restrict__ A, const bf16* __restrict__ B,
                 const float* __restrict__ bias_p, float* __restrict__ out) {
  __shared__ bf16 As[2][8192];                       // 2 x 16 KB
  const int tid = threadIdx.x;
  const int lane = tid & 63, w = tid >> 6;
  const int wm = w >> 1, wn = w & 1;
  const int bid = blockIdx.x;
  const int mb = (bid & 7) * 8 + ((bid >> 3) & 7);   // XCD-chunked swizzle (bijective, 8x8x8)
  const int nb = bid >> 6;

  const bf16* aG = A + (size_t)mb * 128 * 8192 + (w * 4) * 512 + lane * 8;
  const bf16* bG = B + (size_t)nb * 128 * 8192 + wn * 1024 + lane * 8;

  f32x16 acc[2][2];
  #pragma unroll
  for (int a = 0; a < 2; ++a)
    #pragma unroll
    for (int b = 0; b < 2; ++b)
      #pragma unroll
      for (int r = 0; r < 16; ++r) acc[a][b][r] = 0.f;

  bf16x8 bA[4][2], bB[4][2];

  auto issueA = [&](int t, int p) {
    const bf16* g = aG + (size_t)t * 8192;
    #pragma unroll
    for (int c = 0; c < 4; ++c)
      g2lds16(g + c * 512, &As[p][(w * 4 + c) * 512]);
  };
  auto loadB = [&](bf16x8 (&dst)[4][2], int t) {
    const bf16* g = bG + (size_t)t * 8192;
    #pragma unroll
    for (int ks = 0; ks < 4; ++ks)
      #pragma unroll
      for (int nt = 0; nt < 2; ++nt)
        dst[ks][nt] = *(const bf16x8*)(g + (ks * 256 + nt * 64) * 8);
  };

  // prologue: A(0) -> buf0 (oldest 4), then B(0), B(1) (next 16)
  issueA(0, 0);
  loadB(bA, 0);
  loadB(bB, 1);

  auto tilestep = [&](int t, int p, bf16x8 (&cur)[4][2]) {
    const bf16* aL = &As[p][(wm * 128 + lane) * 8];
    if (t + 1 < 128) {
      issueA(t + 1, p ^ 1);
      // outstanding (old->new): B(t)8?,A(t)4?,B(t+1)8,A(t+1)4 -> keep 12 newest
      asm volatile("s_waitcnt vmcnt(12)" ::: "memory");
    } else {
      asm volatile("s_waitcnt vmcnt(0)" ::: "memory");
    }
    __builtin_amdgcn_s_barrier();
    asm volatile("" ::: "memory");
    {                                                // phase 0: ks 0,1
      bf16x8 a00 = *(const bf16x8*)(aL);
      bf16x8 a01 = *(const bf16x8*)(aL + 64 * 8);
      bf16x8 a10 = *(const bf16x8*)(aL + 256 * 8);
      bf16x8 a11 = *(const bf16x8*)(aL + 320 * 8);
      __builtin_amdgcn_s_setprio(1);
      acc[0][0] = MFMA(a00, cur[0][0], acc[0][0], 0, 0, 0);
      acc[0][1] = MFMA(a00, cur[0][1], acc[0][1], 0, 0, 0);
      acc[1][0] = MFMA(a01, cur[0][0], acc[1][0], 0, 0, 0);
      acc[1][1] = MFMA(a01, cur[0][1], acc[1][1], 0, 0, 0);
      acc[0][0] = MFMA(a10, cur[1][0], acc[0][0], 0, 0, 0);
      acc[0][1] = MFMA(a10, cur[1][1], acc[0][1], 0, 0, 0);
      acc[1][0] = MFMA(a11, cur[1][0], acc[1][0], 0, 0, 0);
      acc[1][1] = MFMA(a11, cur[1][1], acc[1][1], 0, 0, 0);
      __builtin_amdgcn_s_setprio(0);
    }
    asm volatile("" ::: "memory");
    __builtin_amdgcn_s_barrier();
    asm volatile("" ::: "memory");
    {                                                // phase 1: ks 2,3
      bf16x8 a20 = *(const bf16x8*)(aL + 512 * 8);
      bf16x8 a21 = *(const bf16x8*)(aL + 576 * 8);
      bf16x8 a30 = *(const bf16x8*)(aL + 768 * 8);
      bf16x8 a31 = *(const bf16x8*)(aL + 832 * 8);
      __builtin_amdgcn_s_setprio(1);
      acc[0][0] = MFMA(a20, cur[2][0], acc[0][0], 0, 0, 0);
      acc[0][1] = MFMA(a20, cur[2][1], acc[0][1], 0, 0, 0);
      acc[1][0] = MFMA(a21, cur[2][0], acc[1][0], 0, 0, 0);
      acc[1][1] = MFMA(a21, cur[2][1], acc[1][1], 0, 0, 0);
      acc[0][0] = MFMA(a30, cur[3][0], acc[0][0], 0, 0, 0);
      acc[0][1] = MFMA(a30, cur[3][1], acc[0][1], 0, 0, 0);
      acc[1][0] = MFMA(a31, cur[3][0], acc[1][0], 0, 0, 0);
      acc[1][1] = MFMA(a31, cur[3][1], acc[1][1], 0, 0, 0);
      __builtin_amdgcn_s_setprio(0);
    }
    if (t + 2 < 128) loadB(cur, t + 2);              // after last use of cur
    asm volatile("" ::: "memory");
    __builtin_amdgcn_s_barrier();                    // readers of As[p] done -> t+2 may overwrite
    asm volatile("" ::: "memory");
  };

  #pragma unroll 1
  for (int t2 = 0; t2 < 128; t2 += 2) {              // x2-unrolled: static buf/reg indices
    tilestep(t2, 0, bA);
    tilestep(t2 + 1, 1, bB);
  }

  // epilogue: C/D layout col=lane&31, row=(r&3)+8*(r>>2)+4*h (verified)
  const int h = lane >> 5, ml = lane & 31;
  const int c0 = nb * 128 + wn * 64 + ml;
  float bv0 = 0.f, bv1 = 0.f;
  #pragma unroll
  for (int p = 0; p < 32; ++p) {
    bv0 += bias_p[(size_t)p * 1024 + c0];
    bv1 += bias_p[(size_t)p * 1024 + c0 + 32];
  }
  #pragma unroll
  for (int mt = 0; mt < 2; ++mt)
    #pragma unroll
    for (int r = 0; r < 16; ++r) {
      int row = mb * 128 + wm * 64 + mt * 32 + (r & 3) + 8 * (r >> 2) + 4 * h;
      float* po = out + (size_t)row * 1024 + c0;
      po[0]  = acc[mt][0][r] + bv0;
      po[32] = acc[mt][1][r] + bv1;
    }
}

// ============================ OLD PATH (fallback, verified 272us) ============================
__global__ __launch_bounds__(256)
void cheby_prep(const float* __restrict__ x, const float* __restrict__ C,
                bf16* __restrict__ Bt, float* __restrict__ bias_p,
                float* __restrict__ th) {
  const int bid = blockIdx.x, tid = threadIdx.x;
  if (bid >= 1024) {
    const int r = bid - 1024;
    f32x4 v = *(const f32x4*)(x + (size_t)r * 1024 + tid * 4);
    f32x4 t;
    #pragma unroll
    for (int j = 0; j < 4; ++j) t[j] = fast_tanh(v[j]);
    *(f32x2*)(th + (size_t)r * 1024 + tid * 2)       = (f32x2){t.x, t.z};
    *(f32x2*)(th + (size_t)r * 1024 + 512 + tid * 2) = (f32x2){t.y, t.w};
    return;
  }
  __shared__ float tile[32][292];
  const int i0 = (bid >> 5) * 32, o0 = (bid & 31) * 32;
  {
    const int r = tid >> 3, seg = tid & 7;
    const float* src = C + (size_t)(i0 + r) * 9216 + (size_t)o0 * 9 + seg * 36;
    float* dst = &tile[r][seg * 36];
    #pragma unroll
    for (int v = 0; v < 9; ++v) *(f32x4*)(dst + v * 4) = *(const f32x4*)(src + v * 4);
  }
  __syncthreads();
  #pragma unroll
  for (int j = 0; j < 4; ++j) {
    int e = tid + 256 * j;
    int il = e >> 5, ol = e & 31;
    int i = i0 + il, o = o0 + ol;
    bf16x8 v;
    #pragma unroll
    for (int d = 0; d < 8; ++d) v[d] = (bf16)tile[il][ol * 9 + 1 + d];
    size_t idx16 = ((size_t)((o >> 7) * 128 + (i >> 3)) * 8 + (i & 7)) * 128 + (o & 127);
    *(bf16x8*)&Bt[idx16 * 8] = v;
  }
  if (tid < 32) {
    float s = 0.f;
    #pragma unroll
    for (int i = 0; i < 32; ++i) s += tile[i][tid * 9];
    bias_p[(size_t)(bid >> 5) * 1024 + o0 + tid] = s;
  }
}

__global__ __launch_bounds__(256, 2)
void cheby_gemm(const float* __restrict__ th, const bf16* __restrict__ Bt,
                const float* __restrict__ bias_p, float* __restrict__ out) {
  __shared__ bf16 Bs[2][8192];
  const int tid  = threadIdx.x;
  const int lane = tid & 63, w = tid >> 6;
  const int wm = w >> 1, wn = w & 1;
  const int nb = blockIdx.x & 7, mb = blockIdx.x >> 3;
  const int t0 = mb * 128, o0 = nb * 128;
  const int ml = lane & 31, h = lane >> 5;

  const float* xr0 = th + (size_t)(t0 + wm * 64 + ml) * 1024 + h * 512;
  const float* xr1 = xr0 + 32 * 1024;
  const bf16* btw = Bt + ((size_t)nb * 128 * 1024 + (size_t)w * 256 + lane) * 8;

  f32x16 acc[2][2];
  #pragma unroll
  for (int a = 0; a < 2; ++a)
    #pragma unroll
    for (int b = 0; b < 2; ++b)
      #pragma unroll
      for (int r = 0; r < 16; ++r) acc[a][b][r] = 0.f;

  bf16x8 afrA[2][4], afrB[2][4];
  f32x4 xv0, xv1;

  auto gen = [&](bf16x8 (&dst)[2][4], f32x4 s0, f32x4 s1) {
    #pragma unroll
    for (int ks = 0; ks < 4; ++ks) {
      f32x2 t  = {s0[ks], s1[ks]};
      f32x2 t2 = t + t;
      f32x2 prev = {1.f, 1.f}, cur = t;
      #pragma unroll
      for (int j = 0; j < 8; ++j) {
        dst[0][ks][j] = (bf16)cur.x;
        dst[1][ks][j] = (bf16)cur.y;
        f32x2 nx = t2 * cur - prev;
        prev = cur; cur = nx;
      }
    }
  };

  {
    f32x4 s0 = *(const f32x4*)(xr0), s1 = *(const f32x4*)(xr1);
    gen(afrA, s0, s1);
    xv0 = *(const f32x4*)(xr0 + 4);
    xv1 = *(const f32x4*)(xr1 + 4);
  }
  #pragma unroll
  for (int b = 0; b < 4; ++b)
    g2lds16(btw + (size_t)b * 64 * 8, &Bs[0][(w * 256 + b * 64) * 8]);

  auto stage = [&](int s, int bi, bf16x8 (&cur)[2][4], bf16x8 (&nxt)[2][4]) {
    __syncthreads();
    if (s < 127) {
      const bf16* g = btw + (size_t)(s + 1) * 8192;
      #pragma unroll
      for (int b = 0; b < 4; ++b)
        g2lds16(g + (size_t)b * 64 * 8, &Bs[bi ^ 1][(w * 256 + b * 64) * 8]);
    }
    bf16x8 bfr[4][2];
    #pragma unroll
    for (int ks = 0; ks < 4; ++ks) {
      const int ce = ((ks * 2 + h) * 128 + wn * 64 + ml) * 8;
      bfr[ks][0] = *(const bf16x8*)&Bs[bi][ce];
      bfr[ks][1] = *(const bf16x8*)&Bs[bi][ce + 32 * 8];
    }
    if (s < 127) {
      gen(nxt, xv0, xv1);
      if (s < 126) {
        xv0 = *(const f32x4*)(xr0 + (s + 2) * 4);
        xv1 = *(const f32x4*)(xr1 + (s + 2) * 4);
      }
    }
    #pragma unroll
    for (int ks = 0; ks < 4; ++ks) {
      acc[0][0] = MFMA(cur[0][ks], bfr[ks][0], acc[0][0], 0, 0, 0);
      acc[0][1] = MFMA(cur[0][ks], bfr[ks][1], acc[0][1], 0, 0, 0);
      acc[1][0] = MFMA(cur[1][ks], bfr[ks][0], acc[1][0], 0, 0, 0);
      acc[1][1] = MFMA(cur[1][ks], bfr[ks][1], acc[1][1], 0, 0, 0);
    }
  };

  #pragma unroll 1
  for (int s2 = 0; s2 < 64; ++s2) {
    stage(2 * s2,     0, afrA, afrB);
    stage(2 * s2 + 1, 1, afrB, afrA);
  }

  const int c0 = o0 + wn * 64 + ml;
  float bv0 = 0.f, bv1 = 0.f;
  #pragma unroll
  for (int p = 0; p < 32; ++p) {
    bv0 += bias_p[(size_t)p * 1024 + c0];
    bv1 += bias_p[(size_t)p * 1024 + c0 + 32];
  }
  #pragma unroll
  for (int mt = 0; mt < 2; ++mt)
    #pragma unroll
    for (int r = 0; r < 16; ++r) {
      int row = t0 + wm * 64 + mt * 32 + (r & 3) + 8 * (r >> 2) + 4 * h;
      float* po = out + (size_t)row * 1024 + c0;
      po[0]  = acc[mt][0][r] + bv0;
      po[32] = acc[mt][1][r] + bv1;
    }
}

// ---- naive fallback (ws too small) — correct, slow, should never run
__global__ __launch_bounds__(256)
void cheby_naive(const float* __restrict__ x, const float* __restrict__ C,
                 float* __restrict__ out) {
  const int t = blockIdx.x, tid = threadIdx.x;
  float acc[4] = {0.f, 0.f, 0.f, 0.f};
  for (int i = 0; i < 1024; ++i) {
    float th = tanhf(x[(size_t)t * 1024 + i]);
    float T[9]; T[0] = 1.f; T[1] = th;
    #pragma unroll
    for (int d = 2; d < 9; ++d) T[d] = 2.f * th * T[d - 1] - T[d - 2];
    #pragma unroll
    for (int j = 0; j < 4; ++j) {
      const float* cp = &C[((size_t)i * 1024 + tid + j * 256) * 9];
      float s = 0.f;
      #pragma unroll
      for (int d = 0; d < 9; ++d) s += T[d] * cp[d];
      acc[j] += s;
    }
  }
  #pragma unroll
  for (int j = 0; j < 4; ++j) out[(size_t)t * 1024 + tid + j * 256] = acc[j];
}

extern "C" void kernel_launch(void* const* d_in, const int* in_sizes, int n_in,
                              void* d_out, int out_size, void* d_ws, size_t ws_size,
                              hipStream_t stream) {
  (void)in_sizes; (void)n_in; (void)out_size;
  const float* x = (const float*)d_in[0];
  const float* C = (const float*)d_in[1];
  float* out = (float*)d_out;

  const size_t a_bytes  = (size_t)8192 * 8192 * 2;        // 134.22 MB
  const size_t b_bytes  = (size_t)8 * 128 * 8192 * 2;     // 16.78 MB
  const size_t bp_bytes = (size_t)32 * 1024 * 4;          // 128 KB

  const size_t bt_bytes = (size_t)8 * 128 * 1024 * 8 * 2; // old path
  const size_t th_bytes = (size_t)8192 * 1024 * 4;

  if (ws_size >= a_bytes + b_bytes + bp_bytes) {
    bf16*  A      = (bf16*)d_ws;
    bf16*  B      = (bf16*)((char*)d_ws + a_bytes);
    float* bias_p = (float*)((char*)d_ws + a_bytes + b_bytes);
    cheby_prep2<<<1536, 256, 0, stream>>>(x, C, A, B, bias_p);
    cheby_gemm2<<<512, 256, 0, stream>>>(A, B, bias_p, out);
  } else if (ws_size >= bt_bytes + bp_bytes + th_bytes) {
    bf16*  Bt     = (bf16*)d_ws;
    float* bias_p = (float*)((char*)d_ws + bt_bytes);
    float* th     = (float*)((char*)d_ws + bt_bytes + bp_bytes);
    cheby_prep<<<9216, 256, 0, stream>>>(x, C, Bt, bias_p, th);
    cheby_gemm<<<512, 256, 0, stream>>>(th, Bt, bias_p, out);
  } else {
    cheby_naive<<<8192, 256, 0, stream>>>(x, C, out);
  }
}